// Round 4
// baseline (1443.572 us; speedup 1.0000x reference)
//
#include <hip/hip_runtime.h>
#include <math.h>

// BracketNet: ctx_{s+1} = GELU_exact(Wc·ctx_s + (b + Wx·x_s)); out = x_s + ctx_{s+1}
// Split: pass1 precomputes z = b + Wx·x (parallel GEMV, -> d_out as scratch);
// pass2 runs the serial chain with only the 64-wide ctx matvec per step,
// broadcasting g across the wave via v_readlane (no LDS, no lgkmcnt stalls).
//
// Round-3 lesson: 128 weight VGPRs exceeded the compiler's budget -> scratch
// spills on the critical path (VGPR_Count=120 < 128 needed). Halving the
// in-loop weight set to 64 VGPRs makes residency actually achievable.

typedef float f32x4 __attribute__((ext_vector_type(4)));

#define S_LEN 2048
#define B_SZ  64
#define D_SZ  512
#define DIM   64
#define STRIDE ((size_t)(B_SZ * D_SZ))   // floats between consecutive s

// ---------------- Pass 1: z[s,b,h,d] = bias[h,d] + sum_k Wx[h,d,k] x[s,b,h,k]
// grid: 64(b) * 8(h) * 4(s-chunk) blocks, 256 threads (4 waves); wave w
// handles s = chunk*512 + w + 4i. Weights pinned in 64 VGPRs; x read as
// wave-broadcast float4 loads (256B/step from HBM, streamed once).
__global__ __launch_bounds__(256, 1) void bracket_pass1(
    const float* __restrict__ src, const float* __restrict__ W,
    const float* __restrict__ bias, float* __restrict__ zout)
{
    const int lane = threadIdx.x & 63;
    const int wv   = threadIdx.x >> 6;          // 0..3
    const int bb   = blockIdx.x & 63;
    const int hh   = (blockIdx.x >> 6) & 7;
    const int ck   = blockIdx.x >> 9;           // 0..3

    f32x4 wx[16];
    {
        const float* wb = W + (size_t)(hh * DIM + lane) * (2 * DIM) + DIM;
#pragma unroll
        for (int i = 0; i < 16; ++i)
            asm volatile("global_load_dwordx4 %0, %1, off offset:%2"
                         : "=v"(wx[i]) : "v"(wb), "i"(16 * i));
    }
    asm volatile("s_waitcnt vmcnt(0)" ::: "memory");
    __builtin_amdgcn_sched_barrier(0);

    const float bv = bias[hh * DIM + lane];
    const float* xb = src  + (size_t)bb * D_SZ + hh * DIM;
    float*       zb = zout + (size_t)bb * D_SZ + hh * DIM + lane;

    const int s0 = ck * 512 + wv;
    for (int i = 0; i < 128; ++i) {
        const int s = s0 + 4 * i;
        const f32x4* xp = (const f32x4*)(xb + (size_t)s * STRIDE);
        float a0 = bv, a1 = 0.f, a2 = 0.f, a3 = 0.f;
        float a4 = 0.f, a5 = 0.f, a6 = 0.f, a7 = 0.f;
#pragma unroll
        for (int j = 0; j < 16; j += 2) {
            const f32x4 u0 = xp[j], u1 = xp[j + 1];
            a0 = fmaf(wx[j].x,     u0.x, a0);
            a1 = fmaf(wx[j].y,     u0.y, a1);
            a2 = fmaf(wx[j].z,     u0.z, a2);
            a3 = fmaf(wx[j].w,     u0.w, a3);
            a4 = fmaf(wx[j + 1].x, u1.x, a4);
            a5 = fmaf(wx[j + 1].y, u1.y, a5);
            a6 = fmaf(wx[j + 1].z, u1.z, a6);
            a7 = fmaf(wx[j + 1].w, u1.w, a7);
        }
        zb[(size_t)s * STRIDE] = ((a0 + a1) + (a2 + a3)) + ((a4 + a5) + (a6 + a7));
    }
}

// ---------------- Pass 2: the serial recurrence, one wave per (b,h) chain.
// g broadcast via v_readlane -> v_fma(sgpr, vgpr): no LDS round-trip.
#define RL(k, comp, accn)                                                     \
    a##accn = fmaf(__int_as_float(__builtin_amdgcn_readlane(gi, (k))),        \
                   w[(k) >> 2].comp, a##accn)
#define G8(m)                                                                 \
    RL(8 * m + 0, x, 0); RL(8 * m + 1, y, 1); RL(8 * m + 2, z, 2);            \
    RL(8 * m + 3, w, 3); RL(8 * m + 4, x, 4); RL(8 * m + 5, y, 5);            \
    RL(8 * m + 6, z, 6); RL(8 * m + 7, w, 7);

__global__ __launch_bounds__(64, 1) void bracket_pass2(
    const float* __restrict__ src, const float* __restrict__ W,
    float* __restrict__ out)   // out holds z on entry; overwritten with result
{
    const int lane = threadIdx.x;
    const int bb   = blockIdx.x >> 3;
    const int hh   = blockIdx.x & 7;

    // Wc row: W[hh*DIM+lane][0:64] -> 16 float4 = 64 VGPRs, pinned.
    f32x4 w[16];
    {
        const float* wb = W + (size_t)(hh * DIM + lane) * (2 * DIM);
#pragma unroll
        for (int i = 0; i < 16; ++i)
            asm volatile("global_load_dwordx4 %0, %1, off offset:%2"
                         : "=v"(w[i]) : "v"(wb), "i"(16 * i));
    }
    asm volatile("s_waitcnt vmcnt(0)" ::: "memory");
    __builtin_amdgcn_sched_barrier(0);

    const float* sp = src + (size_t)bb * D_SZ + hh * DIM + lane;
    float*       op = out + (size_t)bb * D_SZ + hh * DIM + lane;

    // Prefetch pipeline depth 4 for both streams (x from src, z from out).
    float x0 = sp[0],        x1 = sp[STRIDE],     x2 = sp[2 * STRIDE], x3 = sp[3 * STRIDE];
    float z0 = op[0],        z1 = op[STRIDE],     z2 = op[2 * STRIDE], z3 = op[3 * STRIDE];
    const float* px = sp + 4 * STRIDE;
    const float* pz = op + 4 * STRIDE;
    const float* pxl = sp + (size_t)(S_LEN - 1) * STRIDE;
    const float* pzl = op + (size_t)(S_LEN - 1) * STRIDE;

    float g = 0.0f;   // ctx_0 = 0

#define STEP(zc, xc)                                                          \
    do {                                                                      \
        const int gi = __float_as_int(g);                                     \
        float a0 = (zc), a1 = 0.f, a2 = 0.f, a3 = 0.f;                        \
        float a4 = 0.f, a5 = 0.f, a6 = 0.f, a7 = 0.f;                         \
        G8(0); G8(1); G8(2); G8(3); G8(4); G8(5); G8(6); G8(7);               \
        const float y = ((a0 + a1) + (a2 + a3)) + ((a4 + a5) + (a6 + a7));    \
        g = 0.5f * y * (1.0f + erff(y * 0.70710678118654752440f));            \
        *op = (xc) + g;                                                       \
        op += STRIDE;                                                         \
    } while (0)

    for (int s = 0; s < S_LEN; s += 4) {
        float xn, zn;
        xn = *px; zn = *pz;
        px = (px < pxl) ? px + STRIDE : pxl;
        pz = (pz < pzl) ? pz + STRIDE : pzl;
        STEP(z0, x0);
        x0 = x1; x1 = x2; x2 = x3; x3 = xn;
        z0 = z1; z1 = z2; z2 = z3; z3 = zn;

        xn = *px; zn = *pz;
        px = (px < pxl) ? px + STRIDE : pxl;
        pz = (pz < pzl) ? pz + STRIDE : pzl;
        STEP(z0, x0);
        x0 = x1; x1 = x2; x2 = x3; x3 = xn;
        z0 = z1; z1 = z2; z2 = z3; z3 = zn;

        xn = *px; zn = *pz;
        px = (px < pxl) ? px + STRIDE : pxl;
        pz = (pz < pzl) ? pz + STRIDE : pzl;
        STEP(z0, x0);
        x0 = x1; x1 = x2; x2 = x3; x3 = xn;
        z0 = z1; z1 = z2; z2 = z3; z3 = zn;

        xn = *px; zn = *pz;
        px = (px < pxl) ? px + STRIDE : pxl;
        pz = (pz < pzl) ? pz + STRIDE : pzl;
        STEP(z0, x0);
        x0 = x1; x1 = x2; x2 = x3; x3 = xn;
        z0 = z1; z1 = z2; z2 = z3; z3 = zn;
    }
#undef STEP
}

extern "C" void kernel_launch(void* const* d_in, const int* in_sizes, int n_in,
                              void* d_out, int out_size, void* d_ws, size_t ws_size,
                              hipStream_t stream) {
    const float* src = (const float*)d_in[0];
    const float* W   = (const float*)d_in[1];
    const float* b   = (const float*)d_in[2];
    float* out       = (float*)d_out;

    hipLaunchKernelGGL(bracket_pass1, dim3(B_SZ * 8 * 4), dim3(256), 0, stream,
                       src, W, b, out);
    hipLaunchKernelGGL(bracket_pass2, dim3(B_SZ * 8), dim3(64), 0, stream,
                       src, W, out);
}

// Round 6
// 1434.228 us; speedup vs baseline: 1.0065x; 1.0065x over previous
//
#include <hip/hip_runtime.h>
#include <math.h>

// BracketNet: ctx_{s+1} = GELU_exact(Wc·ctx_s + (b + Wx·x_s)); out = x_s + ctx_{s+1}
// pass1: z = b + Wx·x, parallel, coalesced-streamed via LDS ring -> d_out.
// pass2: serial chain, one wave per (b,h); g broadcast via v_readlane;
//        custom branchless erf (A&S 7.1.26, |eps|<=1.5e-7).
//
// Round-5 lesson: the exp builtin is __builtin_amdgcn_exp2f (v_exp_f32 = 2^x).

typedef float f32x4 __attribute__((ext_vector_type(4)));

#define S_LEN 2048
#define B_SZ  64
#define D_SZ  512
#define DIM   64
#define STRIDE ((size_t)(B_SZ * D_SZ))   // floats between consecutive s

// Branchless exact-GELU: 0.5*y*(1+erf(y/sqrt2)), erf via A&S 7.1.26.
__device__ __forceinline__ float gelu_exact(float y) {
    const float ax = fabsf(y) * 0.70710678118654752440f;     // |y|/sqrt(2)
    const float t  = __builtin_amdgcn_rcpf(fmaf(0.3275911f, ax, 1.0f));
    float p = fmaf(1.061405429f, t, -1.453152027f);
    p = fmaf(p, t, 1.421413741f);
    p = fmaf(p, t, -0.284496736f);
    p = fmaf(p, t, 0.254829592f);
    p *= t;
    const float e = __builtin_amdgcn_exp2f(-ax * ax * 1.44269504088896f); // 2^x
    float er = fmaf(-p, e, 1.0f);                            // erf(|x|)
    er = copysignf(er, y);
    return 0.5f * y * (1.0f + er);
}

// ---------------- Pass 1: z[s,b,t] = bias[t] + sum_k Wx[t,k] x[s,b,(t>>6)*64+k]
// 512 threads = full (h,d) plane; block = (b, chunk of 256 s).
__global__ __launch_bounds__(512, 4) void bracket_pass1(
    const float* __restrict__ src, const float* __restrict__ W,
    const float* __restrict__ bias, float* __restrict__ zout)
{
    const int t  = threadIdx.x;           // (h,d): h = t>>6, d = t&63
    const int bb = blockIdx.x & 63;
    const int ck = blockIdx.x >> 6;       // 0..7 (256 s each)

    // Wx row for this (h,d): W[t*128 + 64 .. 128) -> 16 float4, pinned.
    f32x4 wx[16];
    {
        const float* wb = W + (size_t)t * (2 * DIM) + DIM;
#pragma unroll
        for (int i = 0; i < 16; ++i)
            asm volatile("global_load_dwordx4 %0, %1, off offset:%2"
                         : "=v"(wx[i]) : "v"(wb), "i"(16 * i));
    }
    asm volatile("s_waitcnt vmcnt(0)" ::: "memory");
    __builtin_amdgcn_sched_barrier(0);

    const float bv = bias[t];

    __shared__ float xs[4][D_SZ];         // 8 KB ring, prefetch distance 2

    const float* xb = src  + (size_t)(ck * 256) * STRIDE + (size_t)bb * D_SZ + t;
    float*       zb = zout + (size_t)(ck * 256) * STRIDE + (size_t)bb * D_SZ + t;

    // Prologue: stage local s = 0, 1.
    xs[0][t] = xb[0];
    xs[1][t] = xb[STRIDE];
    __syncthreads();

    const int hbase = (t >> 6) << 6;      // wave-uniform head base in xs row

    const float* pp    = xb + 2 * STRIDE;             // next stage: s+2
    const float* plast = xb + 255 * STRIDE;

    for (int i = 0; i < 256; ++i) {
        // Coalesced prefetch of x[s+2] (2KB/block), fire-and-forget.
        const float xn = *pp;
        pp = (pp < plast) ? (pp + STRIDE) : plast;

        const f32x4* xv = (const f32x4*)&xs[i & 3][hbase];  // uniform: broadcast
        float a0 = bv, a1 = 0.f, a2 = 0.f, a3 = 0.f;
        float a4 = 0.f, a5 = 0.f, a6 = 0.f, a7 = 0.f;
#pragma unroll
        for (int j = 0; j < 16; j += 2) {
            const f32x4 u0 = xv[j], u1 = xv[j + 1];
            a0 = fmaf(wx[j].x,     u0.x, a0);
            a1 = fmaf(wx[j].y,     u0.y, a1);
            a2 = fmaf(wx[j].z,     u0.z, a2);
            a3 = fmaf(wx[j].w,     u0.w, a3);
            a4 = fmaf(wx[j + 1].x, u1.x, a4);
            a5 = fmaf(wx[j + 1].y, u1.y, a5);
            a6 = fmaf(wx[j + 1].z, u1.z, a6);
            a7 = fmaf(wx[j + 1].w, u1.w, a7);
        }
        zb[(size_t)i * STRIDE] = ((a0 + a1) + (a2 + a3)) + ((a4 + a5) + (a6 + a7));

        xs[(i + 2) & 3][t] = xn;          // lands 2 iterations ahead
        __syncthreads();
    }
}

// ---------------- Pass 2: the serial recurrence, one wave per (b,h) chain.
#define RL(k, comp, accn)                                                     \
    a##accn = fmaf(__int_as_float(__builtin_amdgcn_readlane(gi, (k))),        \
                   w[(k) >> 2].comp, a##accn)
#define G8(m)                                                                 \
    RL(8 * m + 0, x, 0); RL(8 * m + 1, y, 1); RL(8 * m + 2, z, 2);            \
    RL(8 * m + 3, w, 3); RL(8 * m + 4, x, 4); RL(8 * m + 5, y, 5);            \
    RL(8 * m + 6, z, 6); RL(8 * m + 7, w, 7);

__global__ __launch_bounds__(64, 1) void bracket_pass2(
    const float* __restrict__ src, const float* __restrict__ W,
    float* __restrict__ out)   // out holds z on entry; overwritten with result
{
    const int lane = threadIdx.x;
    const int bb   = blockIdx.x >> 3;
    const int hh   = blockIdx.x & 7;

    // Wc row: W[hh*DIM+lane][0:64] -> 16 float4 = 64 VGPRs, pinned.
    f32x4 w[16];
    {
        const float* wb = W + (size_t)(hh * DIM + lane) * (2 * DIM);
#pragma unroll
        for (int i = 0; i < 16; ++i)
            asm volatile("global_load_dwordx4 %0, %1, off offset:%2"
                         : "=v"(w[i]) : "v"(wb), "i"(16 * i));
    }
    asm volatile("s_waitcnt vmcnt(0)" ::: "memory");
    __builtin_amdgcn_sched_barrier(0);

    const float* sp = src + (size_t)bb * D_SZ + hh * DIM + lane;
    float*       op = out + (size_t)bb * D_SZ + hh * DIM + lane;

    // Prefetch pipeline depth 4 for both streams (x from src, z from out).
    float x0 = sp[0], x1 = sp[STRIDE], x2 = sp[2 * STRIDE], x3 = sp[3 * STRIDE];
    float z0 = op[0], z1 = op[STRIDE], z2 = op[2 * STRIDE], z3 = op[3 * STRIDE];
    const float* px  = sp + 4 * STRIDE;
    const float* pz  = op + 4 * STRIDE;
    const float* pxl = sp + (size_t)(S_LEN - 1) * STRIDE;
    const float* pzl = op + (size_t)(S_LEN - 1) * STRIDE;

    float g = 0.0f;   // ctx_0 = 0

#define STEP(zc, xc)                                                          \
    do {                                                                      \
        const int gi = __float_as_int(g);                                     \
        float a0 = (zc), a1 = 0.f, a2 = 0.f, a3 = 0.f;                        \
        float a4 = 0.f, a5 = 0.f, a6 = 0.f, a7 = 0.f;                         \
        G8(0); G8(1); G8(2); G8(3); G8(4); G8(5); G8(6); G8(7);               \
        const float y = ((a0 + a1) + (a2 + a3)) + ((a4 + a5) + (a6 + a7));    \
        g = gelu_exact(y);                                                    \
        *op = (xc) + g;                                                       \
        op += STRIDE;                                                         \
    } while (0)

    for (int s = 0; s < S_LEN; s += 4) {
        float xn, zn;
        xn = *px; zn = *pz;
        px = (px < pxl) ? px + STRIDE : pxl;
        pz = (pz < pzl) ? pz + STRIDE : pzl;
        STEP(z0, x0);
        x0 = x1; x1 = x2; x2 = x3; x3 = xn;
        z0 = z1; z1 = z2; z2 = z3; z3 = zn;

        xn = *px; zn = *pz;
        px = (px < pxl) ? px + STRIDE : pxl;
        pz = (pz < pzl) ? pz + STRIDE : pzl;
        STEP(z0, x0);
        x0 = x1; x1 = x2; x2 = x3; x3 = xn;
        z0 = z1; z1 = z2; z2 = z3; z3 = zn;

        xn = *px; zn = *pz;
        px = (px < pxl) ? px + STRIDE : pxl;
        pz = (pz < pzl) ? pz + STRIDE : pzl;
        STEP(z0, x0);
        x0 = x1; x1 = x2; x2 = x3; x3 = xn;
        z0 = z1; z1 = z2; z2 = z3; z3 = zn;

        xn = *px; zn = *pz;
        px = (px < pxl) ? px + STRIDE : pxl;
        pz = (pz < pzl) ? pz + STRIDE : pzl;
        STEP(z0, x0);
        x0 = x1; x1 = x2; x2 = x3; x3 = xn;
        z0 = z1; z1 = z2; z2 = z3; z3 = zn;
    }
#undef STEP
}

extern "C" void kernel_launch(void* const* d_in, const int* in_sizes, int n_in,
                              void* d_out, int out_size, void* d_ws, size_t ws_size,
                              hipStream_t stream) {
    const float* src = (const float*)d_in[0];
    const float* W   = (const float*)d_in[1];
    const float* b   = (const float*)d_in[2];
    float* out       = (float*)d_out;

    hipLaunchKernelGGL(bracket_pass1, dim3(B_SZ * 8), dim3(512), 0, stream,
                       src, W, b, out);
    hipLaunchKernelGGL(bracket_pass2, dim3(B_SZ * 8), dim3(64), 0, stream,
                       src, W, out);
}

// Round 7
// 964.814 us; speedup vs baseline: 1.4962x; 1.4865x over previous
//
#include <hip/hip_runtime.h>
#include <math.h>

// BracketNet: ctx_{s+1} = GELU_exact(Wc·ctx_s + (b + Wx·x_s)); out = x_s + ctx_{s+1}
// pass1: z = b + Wx·x, parallel over (b,h,s-chunk), one wave/block, weights in
//        64 VGPRs, x broadcast via v_readlane (no LDS, no barriers).
// pass2: serial chain, one wave per (b,h); identical readlane-GEMV inner loop
//        plus branchless erf GELU; depth-4 prefetch, clamp-free main loop.
//
// Round-6 lesson: __launch_bounds__(512,4) made the allocator target 8 waves/EU
// -> 64 total VGPRs -> all 16 weight quads spilled to scratch (845us pass1).
// 16 volatile-asm weight quads stay resident only in small 1-wave kernels
// ((64,1)/(256,1) observed). Also pass1's LDS ring was intra-wave only ->
// readlane replaces it outright.

typedef float f32x4 __attribute__((ext_vector_type(4)));

#define S_LEN 2048
#define B_SZ  64
#define D_SZ  512
#define DIM   64
#define STRIDE ((size_t)(B_SZ * D_SZ))   // floats between consecutive s

// Branchless exact-GELU: 0.5*y*(1+erf(y/sqrt2)), erf via A&S 7.1.26 (|eps|<=1.5e-7).
__device__ __forceinline__ float gelu_exact(float y) {
    const float ax = fabsf(y) * 0.70710678118654752440f;     // |y|/sqrt(2)
    const float t  = __builtin_amdgcn_rcpf(fmaf(0.3275911f, ax, 1.0f));
    float p = fmaf(1.061405429f, t, -1.453152027f);
    p = fmaf(p, t, 1.421413741f);
    p = fmaf(p, t, -0.284496736f);
    p = fmaf(p, t, 0.254829592f);
    p *= t;
    const float e = __builtin_amdgcn_exp2f(-ax * ax * 1.44269504088896f); // 2^(-x^2*log2e)
    float er = fmaf(-p, e, 1.0f);                            // erf(|x|)
    er = copysignf(er, y);
    return 0.5f * y * (1.0f + er);
}

// Broadcast-GEMV building blocks: lane d accumulates sum_k w[k]·v[k] where
// v[k] = lane k of the VGPR gi (readlane -> SGPR -> v_fma).
#define RL(k, comp, accn)                                                     \
    a##accn = fmaf(__int_as_float(__builtin_amdgcn_readlane(gi, (k))),        \
                   w[(k) >> 2].comp, a##accn)
#define G8(m)                                                                 \
    RL(8 * m + 0, x, 0); RL(8 * m + 1, y, 1); RL(8 * m + 2, z, 2);            \
    RL(8 * m + 3, w, 3); RL(8 * m + 4, x, 4); RL(8 * m + 5, y, 5);            \
    RL(8 * m + 6, z, 6); RL(8 * m + 7, w, 7);
#define G64_REDUCE(y)                                                         \
    G8(0); G8(1); G8(2); G8(3); G8(4); G8(5); G8(6); G8(7);                   \
    const float y = ((a0 + a1) + (a2 + a3)) + ((a4 + a5) + (a6 + a7));

// ---------------- Pass 1: z[s,b,h,d] = bias[h,d] + sum_k Wx[h,d,k] x[s,b,h,k]
// One wave per (b,h,s-chunk of 512); 2048 blocks, 8 waves/CU.
__global__ __launch_bounds__(64, 1) void bracket_pass1(
    const float* __restrict__ src, const float* __restrict__ W,
    const float* __restrict__ bias, float* __restrict__ zout)
{
    const int lane = threadIdx.x;
    const int ck   = blockIdx.x >> 9;          // 0..3 (512 s each)
    const int bb   = (blockIdx.x >> 3) & 63;
    const int hh   = blockIdx.x & 7;

    // Wx row: W[(hh*64+lane)*128 + 64..128) -> 16 float4 = 64 VGPRs, pinned.
    f32x4 w[16];
    {
        const float* wb = W + (size_t)(hh * DIM + lane) * (2 * DIM) + DIM;
#pragma unroll
        for (int i = 0; i < 16; ++i)
            asm volatile("global_load_dwordx4 %0, %1, off offset:%2"
                         : "=v"(w[i]) : "v"(wb), "i"(16 * i));
    }
    asm volatile("s_waitcnt vmcnt(0)" ::: "memory");
    __builtin_amdgcn_sched_barrier(0);

    const float bv = bias[hh * DIM + lane];

    const float* sp = src  + (size_t)(ck * 512) * STRIDE + (size_t)bb * D_SZ + hh * DIM + lane;
    float*       zp = zout + (size_t)(ck * 512) * STRIDE + (size_t)bb * D_SZ + hh * DIM + lane;

    float x0 = sp[0], x1 = sp[STRIDE], x2 = sp[2 * STRIDE], x3 = sp[3 * STRIDE];
    const float* pp = sp + 4 * STRIDE;

#define P1STEP(xc)                                                            \
    do {                                                                      \
        const int gi = __float_as_int(xc);                                    \
        float a0 = bv, a1 = 0.f, a2 = 0.f, a3 = 0.f;                          \
        float a4 = 0.f, a5 = 0.f, a6 = 0.f, a7 = 0.f;                         \
        G64_REDUCE(y);                                                        \
        *zp = y;                                                              \
        zp += STRIDE;                                                         \
    } while (0)

    for (int i = 0; i < 508; i += 4) {
        float xn;
        xn = *pp; pp += STRIDE; P1STEP(x0); x0 = xn;
        xn = *pp; pp += STRIDE; P1STEP(x1); x1 = xn;
        xn = *pp; pp += STRIDE; P1STEP(x2); x2 = xn;
        xn = *pp; pp += STRIDE; P1STEP(x3); x3 = xn;
    }
    P1STEP(x0); P1STEP(x1); P1STEP(x2); P1STEP(x3);
#undef P1STEP
}

// ---------------- Pass 2: the serial recurrence, one wave per (b,h) chain.
__global__ __launch_bounds__(64, 1) void bracket_pass2(
    const float* __restrict__ src, const float* __restrict__ W,
    float* __restrict__ out)   // out holds z on entry; overwritten with result
{
    const int lane = threadIdx.x;
    const int bb   = blockIdx.x >> 3;
    const int hh   = blockIdx.x & 7;

    // Wc row: W[(hh*64+lane)*128 + 0..64) -> 16 float4 = 64 VGPRs, pinned.
    f32x4 w[16];
    {
        const float* wb = W + (size_t)(hh * DIM + lane) * (2 * DIM);
#pragma unroll
        for (int i = 0; i < 16; ++i)
            asm volatile("global_load_dwordx4 %0, %1, off offset:%2"
                         : "=v"(w[i]) : "v"(wb), "i"(16 * i));
    }
    asm volatile("s_waitcnt vmcnt(0)" ::: "memory");
    __builtin_amdgcn_sched_barrier(0);

    const float* sp = src + (size_t)bb * D_SZ + hh * DIM + lane;
    float*       op = out + (size_t)bb * D_SZ + hh * DIM + lane;

    float x0 = sp[0], x1 = sp[STRIDE], x2 = sp[2 * STRIDE], x3 = sp[3 * STRIDE];
    float z0 = op[0], z1 = op[STRIDE], z2 = op[2 * STRIDE], z3 = op[3 * STRIDE];
    const float* px = sp + 4 * STRIDE;
    const float* pz = op + 4 * STRIDE;

    float g = 0.0f;   // ctx_0 = 0

#define STEP(zc, xc)                                                          \
    do {                                                                      \
        const int gi = __float_as_int(g);                                     \
        float a0 = (zc), a1 = 0.f, a2 = 0.f, a3 = 0.f;                        \
        float a4 = 0.f, a5 = 0.f, a6 = 0.f, a7 = 0.f;                         \
        G64_REDUCE(y);                                                        \
        g = gelu_exact(y);                                                    \
        *op = (xc) + g;                                                       \
        op += STRIDE;                                                         \
    } while (0)

    for (int s = 0; s < S_LEN - 4; s += 4) {
        float xn, zn;
        xn = *px; zn = *pz; px += STRIDE; pz += STRIDE;
        STEP(z0, x0); x0 = xn; z0 = zn;
        xn = *px; zn = *pz; px += STRIDE; pz += STRIDE;
        STEP(z1, x1); x1 = xn; z1 = zn;
        xn = *px; zn = *pz; px += STRIDE; pz += STRIDE;
        STEP(z2, x2); x2 = xn; z2 = zn;
        xn = *px; zn = *pz; px += STRIDE; pz += STRIDE;
        STEP(z3, x3); x3 = xn; z3 = zn;
    }
    STEP(z0, x0); STEP(z1, x1); STEP(z2, x2); STEP(z3, x3);
#undef STEP
}

extern "C" void kernel_launch(void* const* d_in, const int* in_sizes, int n_in,
                              void* d_out, int out_size, void* d_ws, size_t ws_size,
                              hipStream_t stream) {
    const float* src = (const float*)d_in[0];
    const float* W   = (const float*)d_in[1];
    const float* b   = (const float*)d_in[2];
    float* out       = (float*)d_out;

    hipLaunchKernelGGL(bracket_pass1, dim3(B_SZ * 8 * 4), dim3(64), 0, stream,
                       src, W, b, out);
    hipLaunchKernelGGL(bracket_pass2, dim3(B_SZ * 8), dim3(64), 0, stream,
                       src, W, out);
}